// Round 3
// baseline (698.360 us; speedup 1.0000x reference)
//
#include <hip/hip_runtime.h>
#include <math.h>

#define WIN 11
#define PAD 5
#define TILE 32
#define VW 42              // V-result width = TILE + 2*PAD
#define H2S 45             // float2 row stride (odd -> conflict-free H reads)
#define NBLK (341 * 48)    // total ssim blocks

struct GW { float g[WIN]; };

// ---------------------------------------------------------------------------
// Fused all-level SSIM, V-pass-first structure.
// Grid (341, 48): blockIdx.x ranges decode level (L0:256,L1:64,L2:16,L3:4,L4:1).
// p=a+b, q=a-b -> 4 conv maps (Mp,Mq,Sp,Sq) suffice.
// V-pass: global->registers (sliding window, 4 y-outputs/item) -> LDS float2.
// H-pass: LDS->registers (sliding window, 4 x-outputs/thread) -> SSIM -> reduce.
// Last finished block computes the final loss (no separate kernel).
// ---------------------------------------------------------------------------
__global__ __launch_bounds__(256, 4) void ssim_all_kernel(
    const float* __restrict__ i1_0, const float* __restrict__ i2_0,
    const float* __restrict__ a1, const float* __restrict__ b1,
    const float* __restrict__ a2, const float* __restrict__ b2,
    const float* __restrict__ a3, const float* __restrict__ b3,
    const float* __restrict__ a4, const float* __restrict__ b4,
    double* __restrict__ acc, float* __restrict__ out, GW gw)
{
    __shared__ float2 h2p[TILE * H2S];   // (Mp, Sp)  11520 B
    __shared__ float2 h2q[TILE * H2S];   // (Mq, Sq)  11520 B
    __shared__ float wsum[4];

    const int tid = threadIdx.x;

    // ---- level decode (wave-uniform) ----
    int bx = blockIdx.x;
    int lvl, tbase;
    if (bx < 256)      { lvl = 0; tbase = 0; }
    else if (bx < 320) { lvl = 1; tbase = 256; }
    else if (bx < 336) { lvl = 2; tbase = 320; }
    else if (bx < 340) { lvl = 3; tbase = 336; }
    else               { lvl = 4; tbase = 340; }
    const int t = bx - tbase;
    const int W = 512 >> lvl;
    const int tiles_x = W >> 5;
    const float* p1; const float* p2;
    switch (lvl) {
      case 0:  p1 = i1_0; p2 = i2_0; break;
      case 1:  p1 = a1;   p2 = b1;   break;
      case 2:  p1 = a2;   p2 = b2;   break;
      case 3:  p1 = a3;   p2 = b3;   break;
      default: p1 = a4;   p2 = b4;   break;
    }
    const size_t imgoff = (size_t)blockIdx.y * W * W;
    p1 += imgoff; p2 += imgoff;

    const int tx = t % tiles_x, ty = t / tiles_x;
    const int X0 = tx * TILE, Y0 = ty * TILE;

    // ---- V-pass: 42 cols x 8 y-groups = 336 items, 4 y-outputs each ----
    for (int item = tid; item < VW * 8; item += 256) {
        int x  = item % VW;          // 0..41 (local col; global gx = X0-5+x)
        int yg = item / VW;          // 0..7
        int gx = X0 - PAD + x;
        bool xin = (unsigned)gx < (unsigned)W;
        int ybase = Y0 + yg * 4 - PAD;
        float Mp[4] = {0.f,0.f,0.f,0.f}, Mq[4] = {0.f,0.f,0.f,0.f};
        float Sp[4] = {0.f,0.f,0.f,0.f}, Sq[4] = {0.f,0.f,0.f,0.f};
#pragma unroll
        for (int j = 0; j < 15; ++j) {
            int gy = ybase + j;
            float a = 0.f, b = 0.f;
            if (xin && (unsigned)gy < (unsigned)W) {
                size_t o = (size_t)gy * W + gx;
                a = p1[o];
                b = p2[o];
            }
            float p = a + b, q = a - b;
            float pp = p * p, qq = q * q;
#pragma unroll
            for (int k = 0; k < 4; ++k) {
                int tap = j - k;
                if (tap >= 0 && tap < WIN) {
                    float g = gw.g[tap];
                    Mp[k] = fmaf(g, p,  Mp[k]);
                    Mq[k] = fmaf(g, q,  Mq[k]);
                    Sp[k] = fmaf(g, pp, Sp[k]);
                    Sq[k] = fmaf(g, qq, Sq[k]);
                }
            }
        }
#pragma unroll
        for (int k = 0; k < 4; ++k) {
            int yl = yg * 4 + k;
            h2p[yl * H2S + x] = make_float2(Mp[k], Sp[k]);
            h2q[yl * H2S + x] = make_float2(Mq[k], Sq[k]);
        }
    }
    __syncthreads();

    // ---- H-pass + SSIM: lane=y fastest (conflict-free), 4 x-outputs/thread --
    const float C1v = 1e-4f;
    const float C2v = 9e-4f;
    float part = 0.f;
    {
        int y  = tid & 31;
        int xg = tid >> 5;                  // 0..7
        const float2* rp = &h2p[y * H2S + xg * 4];
        const float2* rq = &h2q[y * H2S + xg * 4];
        float Mp[4] = {0.f,0.f,0.f,0.f}, Mq[4] = {0.f,0.f,0.f,0.f};
        float Sp[4] = {0.f,0.f,0.f,0.f}, Sq[4] = {0.f,0.f,0.f,0.f};
#pragma unroll
        for (int j = 0; j < 15; ++j) {
            float2 vp = rp[j];
            float2 vq = rq[j];
#pragma unroll
            for (int k = 0; k < 4; ++k) {
                int tap = j - k;
                if (tap >= 0 && tap < WIN) {
                    float g = gw.g[tap];
                    Mp[k] = fmaf(g, vp.x, Mp[k]);
                    Sp[k] = fmaf(g, vp.y, Sp[k]);
                    Mq[k] = fmaf(g, vq.x, Mq[k]);
                    Sq[k] = fmaf(g, vq.y, Sq[k]);
                }
            }
        }
#pragma unroll
        for (int k = 0; k < 4; ++k) {
            float A = Mp[k] * Mp[k];        // Mp^2
            float B = Mq[k] * Mq[k];        // Mq^2
            float ABp = A + B, ABm = A - B;
            float SSp = Sp[k] + Sq[k];
            float SSm = Sp[k] - Sq[k];
            float n1 = fmaf(0.5f, ABm, C1v);        // 2*m12 + C1
            float n2 = fmaf(0.5f, SSm - ABm, C2v);  // 2*s12 + C2
            float e1 = fmaf(0.5f, ABp, C1v);        // m1^2+m2^2 + C1
            float e2 = fmaf(0.5f, SSp - ABp, C2v);  // s1+s2 + C2
            part += (n1 * n2) * __builtin_amdgcn_rcpf(e1 * e2);
        }
    }

    // ---- block reduction + per-level accumulate + last-block finalize ----
#pragma unroll
    for (int off = 32; off > 0; off >>= 1)
        part += __shfl_down(part, off, 64);
    int lane = tid & 63, wv = tid >> 6;
    if (lane == 0) wsum[wv] = part;
    __syncthreads();
    if (tid == 0) {
        float s = wsum[0] + wsum[1] + wsum[2] + wsum[3];
        atomicAdd(acc + lvl, (double)s);
        __threadfence();
        unsigned* cnt = (unsigned*)(acc + 5);
        unsigned done = atomicAdd(cnt, 1u);
        if (done == NBLK - 1) {
            double loss = 0.0;
#pragma unroll
            for (int l = 0; l < 5; ++l) {
                double n = 48.0 * (double)(512 >> l) * (double)(512 >> l);
                double v = atomicAdd(acc + l, 0.0);   // coherent read
                loss += 1.0 - v / n;
            }
            out[0] = (float)loss;
        }
    }
}

// ---------------------------------------------------------------------------
// One-shot pyramid: each block pools a 64x64 region of one image down to
// L1..L4. Grid (64, 96); y = image (0..47 img1, 48..95 img2).
// Block (0,0) zeroes the 5 accumulators + done-counter.
// ---------------------------------------------------------------------------
__global__ __launch_bounds__(256) void pool_all_kernel(
    const float* __restrict__ i1, const float* __restrict__ i2,
    float* __restrict__ a1, float* __restrict__ b1,
    float* __restrict__ a2, float* __restrict__ b2,
    float* __restrict__ a3, float* __restrict__ b3,
    float* __restrict__ a4, float* __restrict__ b4,
    double* __restrict__ acc)
{
    __shared__ float l1[32][33];
    __shared__ float l2[16][17];
    __shared__ float l3[8][9];
    const int tid = threadIdx.x;
    const int im = blockIdx.y;
    const int tb = blockIdx.x;
    const int tx = tb & 7, ty = tb >> 3;
    const bool second = im >= 48;
    const int ii = second ? im - 48 : im;
    const float* src = (second ? i2 : i1) + (size_t)ii * 512 * 512;
    float* o1 = (second ? b1 : a1) + (size_t)ii * 256 * 256;
    float* o2 = (second ? b2 : a2) + (size_t)ii * 128 * 128;
    float* o3 = (second ? b3 : a3) + (size_t)ii * 64 * 64;
    float* o4 = (second ? b4 : a4) + (size_t)ii * 32 * 32;
    const int X0 = tx * 64, Y0 = ty * 64;

    if (blockIdx.x == 0 && blockIdx.y == 0 && tid < 6)
        acc[tid] = 0.0;   // acc[5] covers the done-counter bytes

    // L1: 1024 outputs per block as 512 horizontal pairs (float4 row loads)
#pragma unroll
    for (int k = 0; k < 2; ++k) {
        int idx = tid + k * 256;          // 0..511
        int xp = idx & 15;                // pair column (2 outputs)
        int yo = idx >> 4;                // 0..31
        const float* rp = src + (size_t)(Y0 + 2 * yo) * 512 + (X0 + 4 * xp);
        float4 r0 = *(const float4*)rp;
        float4 r1 = *(const float4*)(rp + 512);
        float v0 = (r0.x + r0.y + r1.x + r1.y) * 0.25f;
        float v1 = (r0.z + r0.w + r1.z + r1.w) * 0.25f;
        l1[yo][2 * xp]     = v0;
        l1[yo][2 * xp + 1] = v1;
        float2* op = (float2*)(o1 + (size_t)((Y0 >> 1) + yo) * 256 + ((X0 >> 1) + 2 * xp));
        *op = make_float2(v0, v1);
    }
    __syncthreads();

    // L2: 16x16
    {
        int xo = tid & 15, yo = tid >> 4;
        float v = (l1[2*yo][2*xo] + l1[2*yo][2*xo+1] +
                   l1[2*yo+1][2*xo] + l1[2*yo+1][2*xo+1]) * 0.25f;
        l2[yo][xo] = v;
        o2[(size_t)((Y0 >> 2) + yo) * 128 + ((X0 >> 2) + xo)] = v;
    }
    __syncthreads();

    // L3: 8x8
    if (tid < 64) {
        int xo = tid & 7, yo = tid >> 3;
        float v = (l2[2*yo][2*xo] + l2[2*yo][2*xo+1] +
                   l2[2*yo+1][2*xo] + l2[2*yo+1][2*xo+1]) * 0.25f;
        l3[yo][xo] = v;
        o3[(size_t)((Y0 >> 3) + yo) * 64 + ((X0 >> 3) + xo)] = v;
    }
    __syncthreads();

    // L4: 4x4
    if (tid < 16) {
        int xo = tid & 3, yo = tid >> 2;
        float v = (l3[2*yo][2*xo] + l3[2*yo][2*xo+1] +
                   l3[2*yo+1][2*xo] + l3[2*yo+1][2*xo+1]) * 0.25f;
        o4[(size_t)((Y0 >> 4) + yo) * 32 + ((X0 >> 4) + xo)] = v;
    }
}

extern "C" void kernel_launch(void* const* d_in, const int* in_sizes, int n_in,
                              void* d_out, int out_size, void* d_ws, size_t ws_size,
                              hipStream_t stream)
{
    const float* img1 = (const float*)d_in[0];
    const float* img2 = (const float*)d_in[1];
    float* out = (float*)d_out;

    // 1D gaussian (sigma=1.5, k=11), matches reference construction
    GW gw;
    double gs[WIN], sum = 0.0;
    for (int i = 0; i < WIN; ++i) {
        double ax = (double)i - 5.0;
        gs[i] = exp(-(ax * ax) / 4.5);
        sum += gs[i];
    }
    for (int i = 0; i < WIN; ++i) gw.g[i] = (float)(gs[i] / sum);

    // workspace: 64B header (5 double acc + counter), then pyramid
    double* acc = (double*)d_ws;
    float* base = (float*)((char*)d_ws + 64);
    const size_t n1 = 48ull * 256 * 256;
    const size_t n2 = 48ull * 128 * 128;
    const size_t n3 = 48ull * 64 * 64;
    const size_t n4 = 48ull * 32 * 32;
    float* a1 = base;      float* b1 = a1 + n1;
    float* a2 = b1 + n1;   float* b2 = a2 + n2;
    float* a3 = b2 + n2;   float* b3 = a3 + n3;
    float* a4 = b3 + n3;   float* b4 = a4 + n4;

    hipLaunchKernelGGL(pool_all_kernel, dim3(64, 96), dim3(256), 0, stream,
                       img1, img2, a1, b1, a2, b2, a3, b3, a4, b4, acc);

    hipLaunchKernelGGL(ssim_all_kernel, dim3(341, 48), dim3(256), 0, stream,
                       img1, img2, a1, b1, a2, b2, a3, b3, a4, b4, acc, out, gw);
}

// Round 4
// 370.227 us; speedup vs baseline: 1.8863x; 1.8863x over previous
//
#include <hip/hip_runtime.h>
#include <math.h>

#define WIN 11
#define PAD 5
#define TILE 32
#define HALO 42            // TILE + WIN - 1
#define PQS 43             // pq row stride in float2 (odd-ish -> clean banks)

struct GW { float g[WIN]; };

// ---------------------------------------------------------------------------
// Fused all-level SSIM. Grid (341, 48): blockIdx.x decodes level
// (L0:256, L1:64, L2:16, L3:4, L4:1 tiles of 32x32 outputs).
// p=a+b, q=a-b -> 4 conv maps (Mp,Mq,Sp,Sq).
// stage (global->LDS pq) -> H-pass (4-col sliding window, b128 h-store)
// -> V-pass (4-row sliding window, conflict-free b32) -> SSIM -> reduce.
// ---------------------------------------------------------------------------
__global__ __launch_bounds__(256, 4) void ssim_all_kernel(
    const float* __restrict__ i1_0, const float* __restrict__ i2_0,
    const float* __restrict__ a1, const float* __restrict__ b1,
    const float* __restrict__ a2, const float* __restrict__ b2,
    const float* __restrict__ a3, const float* __restrict__ b3,
    const float* __restrict__ a4, const float* __restrict__ b4,
    double* __restrict__ acc, GW gw)
{
    __shared__ float2 pq[HALO * PQS];                  // 14448 B
    __shared__ __align__(16) float h[4][HALO][TILE];   // 21504 B
    __shared__ float wsum[4];

    const int tid = threadIdx.x;

    // ---- level decode (block-uniform) ----
    int bx = blockIdx.x;
    int lvl, tbase;
    if (bx < 256)      { lvl = 0; tbase = 0; }
    else if (bx < 320) { lvl = 1; tbase = 256; }
    else if (bx < 336) { lvl = 2; tbase = 320; }
    else if (bx < 340) { lvl = 3; tbase = 336; }
    else               { lvl = 4; tbase = 340; }
    const int t = bx - tbase;
    const int W = 512 >> lvl;
    const int tiles_x = W >> 5;
    const float* p1; const float* p2;
    switch (lvl) {
      case 0:  p1 = i1_0; p2 = i2_0; break;
      case 1:  p1 = a1;   p2 = b1;   break;
      case 2:  p1 = a2;   p2 = b2;   break;
      case 3:  p1 = a3;   p2 = b3;   break;
      default: p1 = a4;   p2 = b4;   break;
    }
    const size_t imgoff = (size_t)blockIdx.y * W * W;
    p1 += imgoff; p2 += imgoff;

    const int tx = t % tiles_x, ty = t / tiles_x;
    const int x0 = tx * TILE - PAD;
    const int y0 = ty * TILE - PAD;

    // ---- stage: (a,b) -> (p,q) into LDS; fast path for interior tiles ----
    const bool interior = (x0 >= 0) && (y0 >= 0) &&
                          (x0 + HALO <= W) && (y0 + HALO <= W);
    if (interior) {
        for (int i = tid; i < HALO * HALO; i += 256) {
            int r = i / HALO, c = i - r * HALO;
            size_t o = (size_t)(y0 + r) * W + (x0 + c);
            float a = p1[o], b = p2[o];
            pq[r * PQS + c] = make_float2(a + b, a - b);
        }
    } else {
        for (int i = tid; i < HALO * HALO; i += 256) {
            int r = i / HALO, c = i - r * HALO;
            int y = y0 + r, x = x0 + c;
            float a = 0.f, b = 0.f;
            if ((unsigned)y < (unsigned)W && (unsigned)x < (unsigned)W) {
                size_t o = (size_t)y * W + x;
                a = p1[o];
                b = p2[o];
            }
            pq[r * PQS + c] = make_float2(a + b, a - b);
        }
    }
    __syncthreads();

    // ---- H-pass: 42 rows x 8 col-groups, 4 consecutive-c outputs/item ----
    for (int i = tid; i < HALO * 8; i += 256) {
        int r = i % HALO, cg = i / HALO;       // lane-fastest r
        int c0 = cg * 4;
        const float2* row = &pq[r * PQS + c0];
        float Mp[4] = {0.f,0.f,0.f,0.f}, Mq[4] = {0.f,0.f,0.f,0.f};
        float Sp[4] = {0.f,0.f,0.f,0.f}, Sq[4] = {0.f,0.f,0.f,0.f};
#pragma unroll
        for (int j = 0; j < 14; ++j) {
            float2 v = row[j];
            float p = v.x, q = v.y;
            float pp = p * p, qq = q * q;
#pragma unroll
            for (int k = 0; k < 4; ++k) {
                int tap = j - k;
                if (tap >= 0 && tap < WIN) {
                    float g = gw.g[tap];
                    Mp[k] = fmaf(g, p,  Mp[k]);
                    Mq[k] = fmaf(g, q,  Mq[k]);
                    Sp[k] = fmaf(g, pp, Sp[k]);
                    Sq[k] = fmaf(g, qq, Sq[k]);
                }
            }
        }
        *(float4*)&h[0][r][c0] = make_float4(Mp[0], Mp[1], Mp[2], Mp[3]);
        *(float4*)&h[1][r][c0] = make_float4(Mq[0], Mq[1], Mq[2], Mq[3]);
        *(float4*)&h[2][r][c0] = make_float4(Sp[0], Sp[1], Sp[2], Sp[3]);
        *(float4*)&h[3][r][c0] = make_float4(Sq[0], Sq[1], Sq[2], Sq[3]);
    }
    __syncthreads();

    // ---- V-pass + SSIM: lane=c (conflict-free), 4 y-outputs/thread ----
    const float C1v = 1e-4f;
    const float C2v = 9e-4f;
    float part = 0.f;
    {
        int c  = tid & 31;
        int r0 = (tid >> 5) << 2;              // 0,4,...,28
        float Mp[4] = {0.f,0.f,0.f,0.f}, Mq[4] = {0.f,0.f,0.f,0.f};
        float Sp[4] = {0.f,0.f,0.f,0.f}, Sq[4] = {0.f,0.f,0.f,0.f};
#pragma unroll
        for (int j = 0; j < 14; ++j) {
            float vmp = h[0][r0 + j][c];
            float vmq = h[1][r0 + j][c];
            float vsp = h[2][r0 + j][c];
            float vsq = h[3][r0 + j][c];
#pragma unroll
            for (int k = 0; k < 4; ++k) {
                int tap = j - k;
                if (tap >= 0 && tap < WIN) {
                    float g = gw.g[tap];
                    Mp[k] = fmaf(g, vmp, Mp[k]);
                    Mq[k] = fmaf(g, vmq, Mq[k]);
                    Sp[k] = fmaf(g, vsp, Sp[k]);
                    Sq[k] = fmaf(g, vsq, Sq[k]);
                }
            }
        }
#pragma unroll
        for (int k = 0; k < 4; ++k) {
            float A = Mp[k] * Mp[k];            // Mp^2
            float B = Mq[k] * Mq[k];            // Mq^2
            float ABp = A + B, ABm = A - B;
            float SSp = Sp[k] + Sq[k];
            float SSm = Sp[k] - Sq[k];
            float n1 = fmaf(0.5f, ABm, C1v);        // 2*m12 + C1
            float n2 = fmaf(0.5f, SSm - ABm, C2v);  // 2*s12 + C2
            float e1 = fmaf(0.5f, ABp, C1v);        // m1^2+m2^2 + C1
            float e2 = fmaf(0.5f, SSp - ABp, C2v);  // s1+s2 + C2
            part += (n1 * n2) * __builtin_amdgcn_rcpf(e1 * e2);
        }
    }

    // ---- block reduction + per-level atomic ----
#pragma unroll
    for (int off = 32; off > 0; off >>= 1)
        part += __shfl_down(part, off, 64);
    int lane = tid & 63, wv = tid >> 6;
    if (lane == 0) wsum[wv] = part;
    __syncthreads();
    if (tid == 0) {
        float s = wsum[0] + wsum[1] + wsum[2] + wsum[3];
        atomicAdd(acc + lvl, (double)s);
    }
}

// ---------------------------------------------------------------------------
// One-shot pyramid: each block pools a 64x64 region of one image to L1..L4.
// Grid (64, 96); y = image (0..47 img1, 48..95 img2). Block (0,0) zeroes acc.
// ---------------------------------------------------------------------------
__global__ __launch_bounds__(256) void pool_all_kernel(
    const float* __restrict__ i1, const float* __restrict__ i2,
    float* __restrict__ a1, float* __restrict__ b1,
    float* __restrict__ a2, float* __restrict__ b2,
    float* __restrict__ a3, float* __restrict__ b3,
    float* __restrict__ a4, float* __restrict__ b4,
    double* __restrict__ acc)
{
    __shared__ float l1[32][33];
    __shared__ float l2[16][17];
    __shared__ float l3[8][9];
    const int tid = threadIdx.x;
    const int im = blockIdx.y;
    const int tb = blockIdx.x;
    const int tx = tb & 7, ty = tb >> 3;
    const bool second = im >= 48;
    const int ii = second ? im - 48 : im;
    const float* src = (second ? i2 : i1) + (size_t)ii * 512 * 512;
    float* o1 = (second ? b1 : a1) + (size_t)ii * 256 * 256;
    float* o2 = (second ? b2 : a2) + (size_t)ii * 128 * 128;
    float* o3 = (second ? b3 : a3) + (size_t)ii * 64 * 64;
    float* o4 = (second ? b4 : a4) + (size_t)ii * 32 * 32;
    const int X0 = tx * 64, Y0 = ty * 64;

    if (blockIdx.x == 0 && blockIdx.y == 0 && tid < 5)
        acc[tid] = 0.0;

    // L1: 1024 outputs/block as 512 horizontal pairs (float4 row loads)
#pragma unroll
    for (int k = 0; k < 2; ++k) {
        int idx = tid + k * 256;          // 0..511
        int xp = idx & 15;                // pair column
        int yo = idx >> 4;                // 0..31
        const float* rp = src + (size_t)(Y0 + 2 * yo) * 512 + (X0 + 4 * xp);
        float4 r0 = *(const float4*)rp;
        float4 r1 = *(const float4*)(rp + 512);
        float v0 = (r0.x + r0.y + r1.x + r1.y) * 0.25f;
        float v1 = (r0.z + r0.w + r1.z + r1.w) * 0.25f;
        l1[yo][2 * xp]     = v0;
        l1[yo][2 * xp + 1] = v1;
        float2* op = (float2*)(o1 + (size_t)((Y0 >> 1) + yo) * 256 + ((X0 >> 1) + 2 * xp));
        *op = make_float2(v0, v1);
    }
    __syncthreads();

    // L2: 16x16
    {
        int xo = tid & 15, yo = tid >> 4;
        float v = (l1[2*yo][2*xo] + l1[2*yo][2*xo+1] +
                   l1[2*yo+1][2*xo] + l1[2*yo+1][2*xo+1]) * 0.25f;
        l2[yo][xo] = v;
        o2[(size_t)((Y0 >> 2) + yo) * 128 + ((X0 >> 2) + xo)] = v;
    }
    __syncthreads();

    // L3: 8x8
    if (tid < 64) {
        int xo = tid & 7, yo = tid >> 3;
        float v = (l2[2*yo][2*xo] + l2[2*yo][2*xo+1] +
                   l2[2*yo+1][2*xo] + l2[2*yo+1][2*xo+1]) * 0.25f;
        l3[yo][xo] = v;
        o3[(size_t)((Y0 >> 3) + yo) * 64 + ((X0 >> 3) + xo)] = v;
    }
    __syncthreads();

    // L4: 4x4
    if (tid < 16) {
        int xo = tid & 3, yo = tid >> 2;
        float v = (l3[2*yo][2*xo] + l3[2*yo][2*xo+1] +
                   l3[2*yo+1][2*xo] + l3[2*yo+1][2*xo+1]) * 0.25f;
        o4[(size_t)((Y0 >> 4) + yo) * 32 + ((X0 >> 4) + xo)] = v;
    }
}

__global__ void final_kernel(const double* __restrict__ acc, float* __restrict__ out)
{
    double loss = 0.0;
#pragma unroll
    for (int l = 0; l < 5; ++l) {
        double cnt = 48.0 * (double)(512 >> l) * (double)(512 >> l);
        loss += 1.0 - acc[l] / cnt;
    }
    out[0] = (float)loss;
}

extern "C" void kernel_launch(void* const* d_in, const int* in_sizes, int n_in,
                              void* d_out, int out_size, void* d_ws, size_t ws_size,
                              hipStream_t stream)
{
    const float* img1 = (const float*)d_in[0];
    const float* img2 = (const float*)d_in[1];
    float* out = (float*)d_out;

    // 1D gaussian (sigma=1.5, k=11), matches reference construction
    GW gw;
    double gs[WIN], sum = 0.0;
    for (int i = 0; i < WIN; ++i) {
        double ax = (double)i - 5.0;
        gs[i] = exp(-(ax * ax) / 4.5);
        sum += gs[i];
    }
    for (int i = 0; i < WIN; ++i) gw.g[i] = (float)(gs[i] / sum);

    // workspace: 64B header (5 double acc), then pyramid
    double* acc = (double*)d_ws;
    float* base = (float*)((char*)d_ws + 64);
    const size_t n1 = 48ull * 256 * 256;
    const size_t n2 = 48ull * 128 * 128;
    const size_t n3 = 48ull * 64 * 64;
    const size_t n4 = 48ull * 32 * 32;
    float* a1 = base;      float* b1 = a1 + n1;
    float* a2 = b1 + n1;   float* b2 = a2 + n2;
    float* a3 = b2 + n2;   float* b3 = a3 + n3;
    float* a4 = b3 + n3;   float* b4 = a4 + n4;

    hipLaunchKernelGGL(pool_all_kernel, dim3(64, 96), dim3(256), 0, stream,
                       img1, img2, a1, b1, a2, b2, a3, b3, a4, b4, acc);

    hipLaunchKernelGGL(ssim_all_kernel, dim3(341, 48), dim3(256), 0, stream,
                       img1, img2, a1, b1, a2, b2, a3, b3, a4, b4, acc, gw);

    hipLaunchKernelGGL(final_kernel, dim3(1), dim3(1), 0, stream, acc, out);
}

// Round 5
// 349.939 us; speedup vs baseline: 1.9957x; 1.0580x over previous
//
#include <hip/hip_runtime.h>
#include <math.h>

#define WIN 11
#define PAD 5
#define TILE 32
#define HALO 42            // TILE + WIN - 1
#define PQS 43             // float2 row stride (odd -> clean banks)

struct GW { float g[WIN]; };

// ---------------------------------------------------------------------------
// Shared tile routine: stage (p=a+b, q=a-b) -> [optional pooled-L1 emit] ->
// H-pass (4-col sliding window, cg in lane-low bits, float2 (M,S) stores) ->
// V-pass (c in lane-low bits, float2 reads, 4-row sliding window) -> SSIM ->
// block reduce -> per-level atomic.
// Bank layout: all LDS arrays are float2 with row stride 43 (odd) and the
// fast-varying index in the lane-low bits -> max 2-way aliasing (free, m136).
// ---------------------------------------------------------------------------
template<bool EMIT>
__device__ __forceinline__ void ssim_tile(
    const float* __restrict__ p1, const float* __restrict__ p2,
    int W, int X0, int Y0, double* __restrict__ accL, const GW& gw,
    float* __restrict__ o1a, float* __restrict__ o1b, int Wout)
{
    __shared__ float2 pq[HALO * PQS];    // (p, q)    14448 B
    __shared__ float2 hA[HALO * PQS];    // (Mp, Sp)  14448 B
    __shared__ float2 hB[HALO * PQS];    // (Mq, Sq)  14448 B
    __shared__ float wsum[4];

    const int tid = threadIdx.x;
    const int x0 = X0 - PAD, y0 = Y0 - PAD;

    // ---- stage ----
    const bool interior = (x0 >= 0) && (y0 >= 0) &&
                          (x0 + HALO <= W) && (y0 + HALO <= W);
    if (interior) {
        for (int i = tid; i < HALO * HALO; i += 256) {
            int r = i / HALO, c = i - r * HALO;
            size_t o = (size_t)(y0 + r) * W + (x0 + c);
            float a = p1[o], b = p2[o];
            pq[r * PQS + c] = make_float2(a + b, a - b);
        }
    } else {
        for (int i = tid; i < HALO * HALO; i += 256) {
            int r = i / HALO, c = i - r * HALO;
            int y = y0 + r, x = x0 + c;
            float a = 0.f, b = 0.f;
            if ((unsigned)y < (unsigned)W && (unsigned)x < (unsigned)W) {
                size_t o = (size_t)y * W + x;
                a = p1[o];
                b = p2[o];
            }
            pq[r * PQS + c] = make_float2(a + b, a - b);
        }
    }
    __syncthreads();

    // ---- optional pooled-L1 emit (L0 blocks only): 16x16 outputs ----
    // pool(a) = (pool(p)+pool(q))/2, pool(b) = (pool(p)-pool(q))/2
    if (EMIT) {
        int xo = tid & 15, yo = tid >> 4;
        const float2* r0p = &pq[(PAD + 2 * yo) * PQS + (PAD + 2 * xo)];
        const float2* r1p = r0p + PQS;
        float2 q00 = r0p[0], q01 = r0p[1], q10 = r1p[0], q11 = r1p[1];
        float P = (q00.x + q01.x + q10.x + q11.x) * 0.25f;
        float Q = (q00.y + q01.y + q10.y + q11.y) * 0.25f;
        size_t oo = (size_t)((Y0 >> 1) + yo) * Wout + ((X0 >> 1) + xo);
        o1a[oo] = (P + Q) * 0.5f;
        o1b[oo] = (P - Q) * 0.5f;
    }

    // ---- H-pass: cg (col-group) in lane-low 3 bits, rows in high bits ----
    {
        const int cg = tid & 7, c0 = cg * 4;
        const int rbase = tid >> 3;             // 0..31
#pragma unroll
        for (int chunk = 0; chunk < 2; ++chunk) {
            int r = rbase + chunk * 32;
            if (r < HALO) {
                const float2* row = &pq[r * PQS + c0];
                float Mp[4] = {0,0,0,0}, Mq[4] = {0,0,0,0};
                float Sp[4] = {0,0,0,0}, Sq[4] = {0,0,0,0};
#pragma unroll
                for (int j = 0; j < 14; ++j) {
                    float2 v = row[j];
                    float p = v.x, q = v.y;
                    float pp = p * p, qq = q * q;
#pragma unroll
                    for (int k = 0; k < 4; ++k) {
                        int t = j - k;
                        if (t >= 0 && t < WIN) {
                            float g = gw.g[t];
                            Mp[k] = fmaf(g, p,  Mp[k]);
                            Mq[k] = fmaf(g, q,  Mq[k]);
                            Sp[k] = fmaf(g, pp, Sp[k]);
                            Sq[k] = fmaf(g, qq, Sq[k]);
                        }
                    }
                }
#pragma unroll
                for (int k = 0; k < 4; ++k) {
                    hA[r * PQS + c0 + k] = make_float2(Mp[k], Sp[k]);
                    hB[r * PQS + c0 + k] = make_float2(Mq[k], Sq[k]);
                }
            }
        }
    }
    __syncthreads();

    // ---- V-pass + SSIM: c in lane-low 5 bits, 4 y-outputs/thread ----
    const float C1v = 1e-4f;
    const float C2v = 9e-4f;
    float part = 0.f;
    {
        const int c  = tid & 31;
        const int r0 = (tid >> 5) << 2;         // 0,4,...,28
        float Mp[4] = {0,0,0,0}, Mq[4] = {0,0,0,0};
        float Sp[4] = {0,0,0,0}, Sq[4] = {0,0,0,0};
#pragma unroll
        for (int j = 0; j < 14; ++j) {
            float2 va = hA[(r0 + j) * PQS + c];
            float2 vb = hB[(r0 + j) * PQS + c];
#pragma unroll
            for (int k = 0; k < 4; ++k) {
                int t = j - k;
                if (t >= 0 && t < WIN) {
                    float g = gw.g[t];
                    Mp[k] = fmaf(g, va.x, Mp[k]);
                    Sp[k] = fmaf(g, va.y, Sp[k]);
                    Mq[k] = fmaf(g, vb.x, Mq[k]);
                    Sq[k] = fmaf(g, vb.y, Sq[k]);
                }
            }
        }
#pragma unroll
        for (int k = 0; k < 4; ++k) {
            float A = Mp[k] * Mp[k];            // Mp^2
            float B = Mq[k] * Mq[k];            // Mq^2
            float ABp = A + B, ABm = A - B;
            float SSp = Sp[k] + Sq[k];
            float SSm = Sp[k] - Sq[k];
            float n1 = fmaf(0.5f, ABm, C1v);        // 2*m12 + C1
            float n2 = fmaf(0.5f, SSm - ABm, C2v);  // 2*s12 + C2
            float e1 = fmaf(0.5f, ABp, C1v);        // m1^2+m2^2 + C1
            float e2 = fmaf(0.5f, SSp - ABp, C2v);  // s1+s2 + C2
            part += (n1 * n2) * __builtin_amdgcn_rcpf(e1 * e2);
        }
    }

    // ---- block reduction + per-level atomic ----
#pragma unroll
    for (int off = 32; off > 0; off >>= 1)
        part += __shfl_down(part, off, 64);
    int lane = tid & 63, wv = tid >> 6;
    if (lane == 0) wsum[wv] = part;
    __syncthreads();
    if (tid == 0) {
        float s = wsum[0] + wsum[1] + wsum[2] + wsum[3];
        atomicAdd(accL, (double)s);
    }
}

// ---- kernel A: L0 SSIM + emit pooled L1 (deletes pool's 100 MB L0 read) ----
__global__ __launch_bounds__(256, 3) void ssim_l0_kernel(
    const float* __restrict__ i1, const float* __restrict__ i2,
    float* __restrict__ a1, float* __restrict__ b1,
    double* __restrict__ acc, GW gw)
{
    const int t = blockIdx.x;                   // 0..255
    const int tx = t & 15, ty = t >> 4;
    const size_t imgoff = (size_t)blockIdx.y * 512 * 512;
    const size_t outoff = (size_t)blockIdx.y * 256 * 256;
    ssim_tile<true>(i1 + imgoff, i2 + imgoff, 512, tx * TILE, ty * TILE,
                    acc, gw, a1 + outoff, b1 + outoff, 256);
}

// ---- kernel C: SSIM for levels 1..4 ----
__global__ __launch_bounds__(256, 3) void ssim_rest_kernel(
    const float* __restrict__ a1, const float* __restrict__ b1,
    const float* __restrict__ a2, const float* __restrict__ b2,
    const float* __restrict__ a3, const float* __restrict__ b3,
    const float* __restrict__ a4, const float* __restrict__ b4,
    double* __restrict__ acc, GW gw)
{
    int bx = blockIdx.x;                        // 0..84
    int lvl, tbase;
    if (bx < 64)      { lvl = 1; tbase = 0; }
    else if (bx < 80) { lvl = 2; tbase = 64; }
    else if (bx < 84) { lvl = 3; tbase = 80; }
    else              { lvl = 4; tbase = 84; }
    const int t = bx - tbase;
    const int W = 512 >> lvl;
    const int tiles_x = W >> 5;
    const float* p1; const float* p2;
    switch (lvl) {
      case 1:  p1 = a1; p2 = b1; break;
      case 2:  p1 = a2; p2 = b2; break;
      case 3:  p1 = a3; p2 = b3; break;
      default: p1 = a4; p2 = b4; break;
    }
    const size_t imgoff = (size_t)blockIdx.y * W * W;
    const int tx = t % tiles_x, ty = t / tiles_x;
    ssim_tile<false>(p1 + imgoff, p2 + imgoff, W, tx * TILE, ty * TILE,
                     acc + lvl, gw, nullptr, nullptr, 0);
}

// ---- kernel B: pool L1 -> L2/L3/L4. Grid (16, 96). ----
__global__ __launch_bounds__(256) void pool_rest_kernel(
    const float* __restrict__ a1, const float* __restrict__ b1,
    float* __restrict__ a2, float* __restrict__ b2,
    float* __restrict__ a3, float* __restrict__ b3,
    float* __restrict__ a4, float* __restrict__ b4)
{
    __shared__ float l2[32][33];
    __shared__ float l3[16][17];
    const int tid = threadIdx.x;
    const int im = blockIdx.y;
    const int tb = blockIdx.x;                  // 0..15 -> 4x4 regions of L1
    const int tx = tb & 3, ty = tb >> 2;
    const bool second = im >= 48;
    const int ii = second ? im - 48 : im;
    const float* src = (second ? b1 : a1) + (size_t)ii * 256 * 256;
    float* o2 = (second ? b2 : a2) + (size_t)ii * 128 * 128;
    float* o3 = (second ? b3 : a3) + (size_t)ii * 64 * 64;
    float* o4 = (second ? b4 : a4) + (size_t)ii * 32 * 32;
    const int X0 = tx * 64, Y0 = ty * 64;       // region origin in L1

    // L2: 32x32 outputs/block, 4 per thread (float4 row-pair loads)
#pragma unroll
    for (int k = 0; k < 2; ++k) {
        int idx = tid + k * 256;                // 0..511 (pair items)
        int xp = idx & 15;                      // pair column
        int yo = idx >> 4;                      // 0..31
        const float* rp = src + (size_t)(Y0 + 2 * yo) * 256 + (X0 + 4 * xp);
        float4 r0 = *(const float4*)rp;
        float4 r1 = *(const float4*)(rp + 256);
        float v0 = (r0.x + r0.y + r1.x + r1.y) * 0.25f;
        float v1 = (r0.z + r0.w + r1.z + r1.w) * 0.25f;
        l2[yo][2 * xp]     = v0;
        l2[yo][2 * xp + 1] = v1;
        float2* op = (float2*)(o2 + (size_t)((Y0 >> 1) + yo) * 128 + ((X0 >> 1) + 2 * xp));
        *op = make_float2(v0, v1);
    }
    __syncthreads();

    // L3: 16x16
    {
        int xo = tid & 15, yo = tid >> 4;
        if (yo < 16) {
            float v = (l2[2*yo][2*xo] + l2[2*yo][2*xo+1] +
                       l2[2*yo+1][2*xo] + l2[2*yo+1][2*xo+1]) * 0.25f;
            l3[yo][xo] = v;
            o3[(size_t)((Y0 >> 2) + yo) * 64 + ((X0 >> 2) + xo)] = v;
        }
    }
    __syncthreads();

    // L4: 8x8
    if (tid < 64) {
        int xo = tid & 7, yo = tid >> 3;
        float v = (l3[2*yo][2*xo] + l3[2*yo][2*xo+1] +
                   l3[2*yo+1][2*xo] + l3[2*yo+1][2*xo+1]) * 0.25f;
        o4[(size_t)((Y0 >> 3) + yo) * 32 + ((X0 >> 3) + xo)] = v;
    }
}

__global__ void final_kernel(const double* __restrict__ acc, float* __restrict__ out)
{
    double loss = 0.0;
#pragma unroll
    for (int l = 0; l < 5; ++l) {
        double cnt = 48.0 * (double)(512 >> l) * (double)(512 >> l);
        loss += 1.0 - acc[l] / cnt;
    }
    out[0] = (float)loss;
}

extern "C" void kernel_launch(void* const* d_in, const int* in_sizes, int n_in,
                              void* d_out, int out_size, void* d_ws, size_t ws_size,
                              hipStream_t stream)
{
    const float* img1 = (const float*)d_in[0];
    const float* img2 = (const float*)d_in[1];
    float* out = (float*)d_out;

    // 1D gaussian (sigma=1.5, k=11), matches reference construction
    GW gw;
    double gs[WIN], sum = 0.0;
    for (int i = 0; i < WIN; ++i) {
        double ax = (double)i - 5.0;
        gs[i] = exp(-(ax * ax) / 4.5);
        sum += gs[i];
    }
    for (int i = 0; i < WIN; ++i) gw.g[i] = (float)(gs[i] / sum);

    // workspace: 64B header (5 double acc), then pyramid
    double* acc = (double*)d_ws;
    float* base = (float*)((char*)d_ws + 64);
    const size_t n1 = 48ull * 256 * 256;
    const size_t n2 = 48ull * 128 * 128;
    const size_t n3 = 48ull * 64 * 64;
    const size_t n4 = 48ull * 32 * 32;
    float* a1 = base;      float* b1 = a1 + n1;
    float* a2 = b1 + n1;   float* b2 = a2 + n2;
    float* a3 = b2 + n2;   float* b3 = a3 + n3;
    float* a4 = b3 + n3;   float* b4 = a4 + n4;

    hipMemsetAsync(acc, 0, 5 * sizeof(double), stream);

    hipLaunchKernelGGL(ssim_l0_kernel, dim3(256, 48), dim3(256), 0, stream,
                       img1, img2, a1, b1, acc, gw);

    hipLaunchKernelGGL(pool_rest_kernel, dim3(16, 96), dim3(256), 0, stream,
                       a1, b1, a2, b2, a3, b3, a4, b4);

    hipLaunchKernelGGL(ssim_rest_kernel, dim3(85, 48), dim3(256), 0, stream,
                       a1, b1, a2, b2, a3, b3, a4, b4, acc, gw);

    hipLaunchKernelGGL(final_kernel, dim3(1), dim3(1), 0, stream, acc, out);
}

// Round 6
// 339.858 us; speedup vs baseline: 2.0549x; 1.0297x over previous
//
#include <hip/hip_runtime.h>
#include <math.h>

#define WIN 11
#define PAD 5
#define TILE 32
#define HALO 42            // TILE + WIN - 1
#define PQS 43             // pq row stride in float2 (odd -> clean banks)
#define HS 34              // h row stride in float2 (even -> b128-capable, clean)

struct GW { float g[WIN]; };

// ---------------------------------------------------------------------------
// Tile routine, two-pass structure for occupancy:
//   stage (p=a+b,q=a-b -> LDS pq) -> [optional pooled-L1 emit]
//   pass m=0: H-conv of p,p^2 -> h -> V-conv -> (Mp,Sp) in regs
//   pass m=1: same for q -> (Mq,Sq) -> SSIM -> block reduce -> atomic.
// One shared h buffer (42x34 float2) instead of two -> 25.9 KB LDS
// -> 6 blocks/CU (vs 3 at 43.5 KB). All LDS access patterns at bank floor.
// ---------------------------------------------------------------------------
template<bool EMIT>
__device__ __forceinline__ void ssim_tile(
    const float* __restrict__ p1, const float* __restrict__ p2,
    int W, int X0, int Y0, double* __restrict__ accL, const GW& gw,
    float* __restrict__ o1a, float* __restrict__ o1b, int Wout)
{
    __shared__ float2 pq[HALO * PQS];                 // 14448 B
    __shared__ __align__(16) float2 h[HALO * HS];     // 11424 B
    __shared__ float wsum[4];

    const int tid = threadIdx.x;
    const int x0 = X0 - PAD, y0 = Y0 - PAD;

    // ---- stage ----
    const bool interior = (x0 >= 0) && (y0 >= 0) &&
                          (x0 + HALO <= W) && (y0 + HALO <= W);
    if (interior) {
        for (int i = tid; i < HALO * HALO; i += 256) {
            int r = i / HALO, c = i - r * HALO;
            size_t o = (size_t)(y0 + r) * W + (x0 + c);
            float a = p1[o], b = p2[o];
            pq[r * PQS + c] = make_float2(a + b, a - b);
        }
    } else {
        for (int i = tid; i < HALO * HALO; i += 256) {
            int r = i / HALO, c = i - r * HALO;
            int y = y0 + r, x = x0 + c;
            float a = 0.f, b = 0.f;
            if ((unsigned)y < (unsigned)W && (unsigned)x < (unsigned)W) {
                size_t o = (size_t)y * W + x;
                a = p1[o];
                b = p2[o];
            }
            pq[r * PQS + c] = make_float2(a + b, a - b);
        }
    }
    __syncthreads();

    // ---- optional pooled-L1 emit (L0 only): 16x16 outputs ----
    // pool(a) = (pool(p)+pool(q))/2, pool(b) = (pool(p)-pool(q))/2
    if (EMIT) {
        int xo = tid & 15, yo = tid >> 4;
        const float2* r0p = &pq[(PAD + 2 * yo) * PQS + (PAD + 2 * xo)];
        const float2* r1p = r0p + PQS;
        float2 q00 = r0p[0], q01 = r0p[1], q10 = r1p[0], q11 = r1p[1];
        float P = (q00.x + q01.x + q10.x + q11.x) * 0.25f;
        float Q = (q00.y + q01.y + q10.y + q11.y) * 0.25f;
        size_t oo = (size_t)((Y0 >> 1) + yo) * Wout + ((X0 >> 1) + xo);
        o1a[oo] = (P + Q) * 0.5f;
        o1b[oo] = (P - Q) * 0.5f;
    }

    float Mv[2][4], Sv[2][4];

#pragma unroll
    for (int m = 0; m < 2; ++m) {
        // ---- H-pass for component m: cg in lane-low 3 bits ----
        {
            const int cg = tid & 7, c0 = cg * 4;
            const int rbase = tid >> 3;           // 0..31
#pragma unroll
            for (int chunk = 0; chunk < 2; ++chunk) {
                int r = rbase + chunk * 32;
                if (r < HALO) {
                    const float2* row = &pq[r * PQS + c0];
                    float M[4] = {0,0,0,0}, S[4] = {0,0,0,0};
#pragma unroll
                    for (int j = 0; j < 14; ++j) {
                        float2 v = row[j];
                        float x = m ? v.y : v.x;
                        float xx = x * x;
#pragma unroll
                        for (int k = 0; k < 4; ++k) {
                            int t = j - k;
                            if (t >= 0 && t < WIN) {
                                float g = gw.g[t];
                                M[k] = fmaf(g, x,  M[k]);
                                S[k] = fmaf(g, xx, S[k]);
                            }
                        }
                    }
                    float2* hp = &h[r * HS + c0];
                    *(float4*)(hp)     = make_float4(M[0], S[0], M[1], S[1]);
                    *(float4*)(hp + 2) = make_float4(M[2], S[2], M[3], S[3]);
                }
            }
        }
        __syncthreads();

        // ---- V-pass: c in lane-low 5 bits, 4 y-outputs/thread ----
        {
            const int c  = tid & 31;
            const int r0 = (tid >> 5) << 2;       // 0,4,...,28
            float M[4] = {0,0,0,0}, S[4] = {0,0,0,0};
#pragma unroll
            for (int j = 0; j < 14; ++j) {
                float2 v = h[(r0 + j) * HS + c];
#pragma unroll
                for (int k = 0; k < 4; ++k) {
                    int t = j - k;
                    if (t >= 0 && t < WIN) {
                        float g = gw.g[t];
                        M[k] = fmaf(g, v.x, M[k]);
                        S[k] = fmaf(g, v.y, S[k]);
                    }
                }
            }
#pragma unroll
            for (int k = 0; k < 4; ++k) { Mv[m][k] = M[k]; Sv[m][k] = S[k]; }
        }
        if (m == 0) __syncthreads();   // h reused by pass 1
    }

    // ---- SSIM combine ----
    const float C1v = 1e-4f;
    const float C2v = 9e-4f;
    float part = 0.f;
#pragma unroll
    for (int k = 0; k < 4; ++k) {
        float A = Mv[0][k] * Mv[0][k];          // Mp^2
        float B = Mv[1][k] * Mv[1][k];          // Mq^2
        float ABp = A + B, ABm = A - B;
        float SSp = Sv[0][k] + Sv[1][k];
        float SSm = Sv[0][k] - Sv[1][k];
        float n1 = fmaf(0.5f, ABm, C1v);        // 2*m12 + C1
        float n2 = fmaf(0.5f, SSm - ABm, C2v);  // 2*s12 + C2
        float e1 = fmaf(0.5f, ABp, C1v);        // m1^2+m2^2 + C1
        float e2 = fmaf(0.5f, SSp - ABp, C2v);  // s1+s2 + C2
        part += (n1 * n2) * __builtin_amdgcn_rcpf(e1 * e2);
    }

    // ---- block reduction + per-level atomic ----
#pragma unroll
    for (int off = 32; off > 0; off >>= 1)
        part += __shfl_down(part, off, 64);
    int lane = tid & 63, wv = tid >> 6;
    if (lane == 0) wsum[wv] = part;
    __syncthreads();
    if (tid == 0) {
        float s = wsum[0] + wsum[1] + wsum[2] + wsum[3];
        atomicAdd(accL, (double)s);
    }
}

// ---- kernel A: L0 SSIM + emit pooled L1 ----
__global__ __launch_bounds__(256, 6) void ssim_l0_kernel(
    const float* __restrict__ i1, const float* __restrict__ i2,
    float* __restrict__ a1, float* __restrict__ b1,
    double* __restrict__ acc, GW gw)
{
    const int t = blockIdx.x;                   // 0..255
    const int tx = t & 15, ty = t >> 4;
    const size_t imgoff = (size_t)blockIdx.y * 512 * 512;
    const size_t outoff = (size_t)blockIdx.y * 256 * 256;
    ssim_tile<true>(i1 + imgoff, i2 + imgoff, 512, tx * TILE, ty * TILE,
                    acc, gw, a1 + outoff, b1 + outoff, 256);
}

// ---- kernel C: SSIM for levels 1..4 ----
__global__ __launch_bounds__(256, 6) void ssim_rest_kernel(
    const float* __restrict__ a1, const float* __restrict__ b1,
    const float* __restrict__ a2, const float* __restrict__ b2,
    const float* __restrict__ a3, const float* __restrict__ b3,
    const float* __restrict__ a4, const float* __restrict__ b4,
    double* __restrict__ acc, GW gw)
{
    int bx = blockIdx.x;                        // 0..84
    int lvl, tbase;
    if (bx < 64)      { lvl = 1; tbase = 0; }
    else if (bx < 80) { lvl = 2; tbase = 64; }
    else if (bx < 84) { lvl = 3; tbase = 80; }
    else              { lvl = 4; tbase = 84; }
    const int t = bx - tbase;
    const int W = 512 >> lvl;
    const int tiles_x = W >> 5;
    const float* p1; const float* p2;
    switch (lvl) {
      case 1:  p1 = a1; p2 = b1; break;
      case 2:  p1 = a2; p2 = b2; break;
      case 3:  p1 = a3; p2 = b3; break;
      default: p1 = a4; p2 = b4; break;
    }
    const size_t imgoff = (size_t)blockIdx.y * W * W;
    const int tx = t % tiles_x, ty = t / tiles_x;
    ssim_tile<false>(p1 + imgoff, p2 + imgoff, W, tx * TILE, ty * TILE,
                     acc + lvl, gw, nullptr, nullptr, 0);
}

// ---- kernel B: pool L1 -> L2/L3/L4. Grid (16, 96). ----
__global__ __launch_bounds__(256) void pool_rest_kernel(
    const float* __restrict__ a1, const float* __restrict__ b1,
    float* __restrict__ a2, float* __restrict__ b2,
    float* __restrict__ a3, float* __restrict__ b3,
    float* __restrict__ a4, float* __restrict__ b4)
{
    __shared__ float l2[32][33];
    __shared__ float l3[16][17];
    const int tid = threadIdx.x;
    const int im = blockIdx.y;
    const int tb = blockIdx.x;                  // 0..15 -> 4x4 regions of L1
    const int tx = tb & 3, ty = tb >> 2;
    const bool second = im >= 48;
    const int ii = second ? im - 48 : im;
    const float* src = (second ? b1 : a1) + (size_t)ii * 256 * 256;
    float* o2 = (second ? b2 : a2) + (size_t)ii * 128 * 128;
    float* o3 = (second ? b3 : a3) + (size_t)ii * 64 * 64;
    float* o4 = (second ? b4 : a4) + (size_t)ii * 32 * 32;
    const int X0 = tx * 64, Y0 = ty * 64;       // region origin in L1

    // L2: 32x32 outputs/block, 4 per thread (float4 row-pair loads)
#pragma unroll
    for (int k = 0; k < 2; ++k) {
        int idx = tid + k * 256;                // 0..511 (pair items)
        int xp = idx & 15;
        int yo = idx >> 4;
        const float* rp = src + (size_t)(Y0 + 2 * yo) * 256 + (X0 + 4 * xp);
        float4 r0 = *(const float4*)rp;
        float4 r1 = *(const float4*)(rp + 256);
        float v0 = (r0.x + r0.y + r1.x + r1.y) * 0.25f;
        float v1 = (r0.z + r0.w + r1.z + r1.w) * 0.25f;
        l2[yo][2 * xp]     = v0;
        l2[yo][2 * xp + 1] = v1;
        float2* op = (float2*)(o2 + (size_t)((Y0 >> 1) + yo) * 128 + ((X0 >> 1) + 2 * xp));
        *op = make_float2(v0, v1);
    }
    __syncthreads();

    // L3: 16x16
    {
        int xo = tid & 15, yo = tid >> 4;
        if (yo < 16) {
            float v = (l2[2*yo][2*xo] + l2[2*yo][2*xo+1] +
                       l2[2*yo+1][2*xo] + l2[2*yo+1][2*xo+1]) * 0.25f;
            l3[yo][xo] = v;
            o3[(size_t)((Y0 >> 2) + yo) * 64 + ((X0 >> 2) + xo)] = v;
        }
    }
    __syncthreads();

    // L4: 8x8
    if (tid < 64) {
        int xo = tid & 7, yo = tid >> 3;
        float v = (l3[2*yo][2*xo] + l3[2*yo][2*xo+1] +
                   l3[2*yo+1][2*xo] + l3[2*yo+1][2*xo+1]) * 0.25f;
        o4[(size_t)((Y0 >> 3) + yo) * 32 + ((X0 >> 3) + xo)] = v;
    }
}

__global__ void final_kernel(const double* __restrict__ acc, float* __restrict__ out)
{
    double loss = 0.0;
#pragma unroll
    for (int l = 0; l < 5; ++l) {
        double cnt = 48.0 * (double)(512 >> l) * (double)(512 >> l);
        loss += 1.0 - acc[l] / cnt;
    }
    out[0] = (float)loss;
}

extern "C" void kernel_launch(void* const* d_in, const int* in_sizes, int n_in,
                              void* d_out, int out_size, void* d_ws, size_t ws_size,
                              hipStream_t stream)
{
    const float* img1 = (const float*)d_in[0];
    const float* img2 = (const float*)d_in[1];
    float* out = (float*)d_out;

    // 1D gaussian (sigma=1.5, k=11), matches reference construction
    GW gw;
    double gs[WIN], sum = 0.0;
    for (int i = 0; i < WIN; ++i) {
        double ax = (double)i - 5.0;
        gs[i] = exp(-(ax * ax) / 4.5);
        sum += gs[i];
    }
    for (int i = 0; i < WIN; ++i) gw.g[i] = (float)(gs[i] / sum);

    // workspace: 64B header (5 double acc), then pyramid
    double* acc = (double*)d_ws;
    float* base = (float*)((char*)d_ws + 64);
    const size_t n1 = 48ull * 256 * 256;
    const size_t n2 = 48ull * 128 * 128;
    const size_t n3 = 48ull * 64 * 64;
    const size_t n4 = 48ull * 32 * 32;
    float* a1 = base;      float* b1 = a1 + n1;
    float* a2 = b1 + n1;   float* b2 = a2 + n2;
    float* a3 = b2 + n2;   float* b3 = a3 + n3;
    float* a4 = b3 + n3;   float* b4 = a4 + n4;

    hipMemsetAsync(acc, 0, 5 * sizeof(double), stream);

    hipLaunchKernelGGL(ssim_l0_kernel, dim3(256, 48), dim3(256), 0, stream,
                       img1, img2, a1, b1, acc, gw);

    hipLaunchKernelGGL(pool_rest_kernel, dim3(16, 96), dim3(256), 0, stream,
                       a1, b1, a2, b2, a3, b3, a4, b4);

    hipLaunchKernelGGL(ssim_rest_kernel, dim3(85, 48), dim3(256), 0, stream,
                       a1, b1, a2, b2, a3, b3, a4, b4, acc, gw);

    hipLaunchKernelGGL(final_kernel, dim3(1), dim3(1), 0, stream, acc, out);
}